// Round 7
// baseline (748.226 us; speedup 1.0000x reference)
//
#include <hip/hip_runtime.h>
#include <hip/hip_fp16.h>
#include <cstdint>
#include <cstddef>

constexpr int NN  = 100000;
constexpr int EE  = 1600000;
constexpr int HID = 128;
constexpr int NBUK = (NN + 511) / 512;        // 196 buckets of 512 nodes
constexpr int BLKE = 2048;                    // edges per block in bucket passes
constexpr int NBE  = (EE + BLKE - 1) / BLKE;  // 782 edge blocks
constexpr int MH   = NBUK * NBE;              // 153272 flattened hist entries
constexpr int NSC  = (MH + 1023) / 1024;      // 150 scan chunks

typedef float    f32x4 __attribute__((ext_vector_type(4)));
typedef _Float16 f16x8 __attribute__((ext_vector_type(8)));

// ---------------------------------------------------------------- pass 1: per-block bucket histograms (LDS atomics only)
__global__ __launch_bounds__(256) void bh_both_k(const int* __restrict__ src, const int* __restrict__ dst,
                                                 int* __restrict__ bh_d, int* __restrict__ bh_s) {
    __shared__ int hd[NBUK], hs[NBUK];
    int blk = blockIdx.x, t = threadIdx.x;
    for (int i = t; i < NBUK; i += 256) { hd[i] = 0; hs[i] = 0; }
    __syncthreads();
    int e0 = blk * BLKE, e1 = min(e0 + BLKE, EE);
    for (int e = e0 + t; e < e1; e += 256) {
        atomicAdd(&hd[dst[e] >> 9], 1);
        atomicAdd(&hs[src[e] >> 9], 1);
    }
    __syncthreads();
    for (int i = t; i < NBUK; i += 256) {
        bh_d[i * NBE + blk] = hd[i];
        bh_s[i * NBE + blk] = hs[i];
    }
}

// ---------------------------------------------------------------- generic 3-level exclusive scan (length n)
__global__ __launch_bounds__(256) void scan_sum_k(const int* __restrict__ in, int* __restrict__ bsum, int n) {
    __shared__ int sc[256];
    int b = blockIdx.x, t = threadIdx.x;
    int base = b * 1024 + t * 4;
    int s = 0;
#pragma unroll
    for (int j = 0; j < 4; j++) { int idx = base + j; s += (idx < n) ? in[idx] : 0; }
    sc[t] = s; __syncthreads();
    for (int off = 128; off > 0; off >>= 1) {
        if (t < off) sc[t] += sc[t + off];
        __syncthreads();
    }
    if (t == 0) bsum[b] = sc[0];
}

__global__ void scan_top_k(const int* __restrict__ bsum, int* __restrict__ boff, int nb) {
    __shared__ int sc[256];
    int t = threadIdx.x;
    int v = (t < nb) ? bsum[t] : 0;
    sc[t] = v; __syncthreads();
    for (int off = 1; off < 256; off <<= 1) {
        int u = (t >= off) ? sc[t - off] : 0;
        __syncthreads();
        sc[t] += u;
        __syncthreads();
    }
    if (t < nb) boff[t] = sc[t] - v;
}

__global__ __launch_bounds__(256) void scan_chunk_k(const int* __restrict__ in, const int* __restrict__ boff,
                                                    int* __restrict__ out, int n) {
    __shared__ int sc[256];
    int b = blockIdx.x, t = threadIdx.x;
    int base = b * 1024 + t * 4;
    int c[4];
#pragma unroll
    for (int j = 0; j < 4; j++) { int idx = base + j; c[j] = (idx < n) ? in[idx] : 0; }
    int s = c[0] + c[1] + c[2] + c[3];
    sc[t] = s; __syncthreads();
    for (int off = 1; off < 256; off <<= 1) {
        int v = (t >= off) ? sc[t - off] : 0;
        __syncthreads();
        sc[t] += v;
        __syncthreads();
    }
    int excl = sc[t] - s + boff[b];
#pragma unroll
    for (int j = 0; j < 4; j++) {
        int idx = base + j;
        if (idx < n) out[idx] = excl;
        excl += c[j];
    }
}

// ---------------------------------------------------------------- pass 2: scatter into bucket order (LDS cursors)
__global__ __launch_bounds__(256) void scatter_both_k(const int* __restrict__ src, const int* __restrict__ dst,
                                                      const int* __restrict__ off_d, const int* __restrict__ off_s,
                                                      int2* __restrict__ pairs, int* __restrict__ ssorted) {
    __shared__ int cd[NBUK], cs[NBUK];
    int blk = blockIdx.x, t = threadIdx.x;
    for (int i = t; i < NBUK; i += 256) {
        cd[i] = off_d[i * NBE + blk];
        cs[i] = off_s[i * NBE + blk];
    }
    __syncthreads();
    int e0 = blk * BLKE, e1 = min(e0 + BLKE, EE);
    for (int e = e0 + t; e < e1; e += 256) {
        int d = dst[e], s = src[e];
        int pd = atomicAdd(&cd[d >> 9], 1);
        pairs[pd] = make_int2(d, s);
        int ps = atomicAdd(&cs[s >> 9], 1);
        ssorted[ps] = s;
    }
}

// ---------------------------------------------------------------- per-bucket: exact in-deg hist -> inorm, rowptr, col
__global__ __launch_bounds__(256) void bucket_csr_k(const int2* __restrict__ pairs, const int* __restrict__ off_d,
                                                    int* __restrict__ rowptr, int* __restrict__ col,
                                                    float* __restrict__ inorm) {
    __shared__ int hist[512];
    __shared__ int excl[512];
    __shared__ int psum[256];
    int b = blockIdx.x, t = threadIdx.x;
    int base = off_d[b * NBE];
    int endv = (b == NBUK - 1) ? EE : off_d[(b + 1) * NBE];
    hist[t] = 0; hist[t + 256] = 0;
    __syncthreads();
    for (int i = base + t; i < endv; i += 256) atomicAdd(&hist[pairs[i].x & 511], 1);
    __syncthreads();
    int p0 = hist[2 * t], p1 = hist[2 * t + 1];
    int ps = p0 + p1;
    psum[t] = ps; __syncthreads();
    for (int off = 1; off < 256; off <<= 1) {
        int u = (t >= off) ? psum[t - off] : 0;
        __syncthreads();
        psum[t] += u;
        __syncthreads();
    }
    int pex = psum[t] - ps;
    excl[2 * t] = pex; excl[2 * t + 1] = pex + p0;
    __syncthreads();
    int n0 = b * 512;
#pragma unroll
    for (int j = 0; j < 2; j++) {
        int i = 2 * t + j, node = n0 + i;
        if (node < NN) {
            rowptr[node] = base + excl[i];
            int c = hist[i]; if (c < 1) c = 1;
            inorm[node] = rsqrtf((float)c);
        }
    }
    if (b == NBUK - 1 && t == 0) rowptr[NN] = EE;
    __syncthreads();
    for (int i = base + t; i < endv; i += 256) {
        int2 p = pairs[i];
        int pos = base + atomicAdd(&excl[p.x & 511], 1);
        col[pos] = p.y;
    }
}

// ---------------------------------------------------------------- per-bucket: exact out-deg hist -> onorm
__global__ __launch_bounds__(256) void bucket_ocnt_k(const int* __restrict__ ssorted, const int* __restrict__ off_s,
                                                     float* __restrict__ onorm) {
    __shared__ int hist[512];
    int b = blockIdx.x, t = threadIdx.x;
    int base = off_s[b * NBE];
    int endv = (b == NBUK - 1) ? EE : off_s[(b + 1) * NBE];
    hist[t] = 0; hist[t + 256] = 0;
    __syncthreads();
    for (int i = base + t; i < endv; i += 256) atomicAdd(&hist[ssorted[i] & 511], 1);
    __syncthreads();
#pragma unroll
    for (int j = 0; j < 2; j++) {
        int i = t + j * 256, node = b * 512 + i;
        if (node < NN) {
            int c = hist[i]; if (c < 1) c = 1;
            onorm[node] = rsqrtf((float)c);
        }
    }
}

// ---------------------------------------------------------------- W12 = W1 @ W2 ; b12 = b1 @ W2 + b2
__global__ __launch_bounds__(256) void w12_k(const float* __restrict__ W1, const float* __restrict__ W2,
                                             float* __restrict__ W12) {
    int idx = blockIdx.x * 256 + threadIdx.x;   // 0..16383
    int i = idx >> 7, j = idx & 127;
    float a0 = 0.f, a1 = 0.f, a2 = 0.f, a3 = 0.f;
    for (int k = 0; k < 128; k += 4) {
        a0 = fmaf(W1[i * 128 + k],     W2[(k)     * 128 + j], a0);
        a1 = fmaf(W1[i * 128 + k + 1], W2[(k + 1) * 128 + j], a1);
        a2 = fmaf(W1[i * 128 + k + 2], W2[(k + 2) * 128 + j], a2);
        a3 = fmaf(W1[i * 128 + k + 3], W2[(k + 3) * 128 + j], a3);
    }
    W12[idx] = (a0 + a1) + (a2 + a3);
}

__global__ void b12_k(const float* __restrict__ b1, const float* __restrict__ W2,
                      const float* __restrict__ b2, float* __restrict__ b12) {
    int j = threadIdx.x;
    if (j < 128) {
        float acc = b2[j];
        for (int k = 0; k < 128; k++) acc = fmaf(b1[k], W2[k * 128 + j], acc);
        b12[j] = acc;
    }
}

// ---------------------------------------------------------------- x -> fp16 hi/lo planes (hi + lo ~= x to ~2^-22 rel)
__global__ __launch_bounds__(256) void split_k(const float* __restrict__ x, _Float16* __restrict__ hi,
                                               _Float16* __restrict__ lo) {
    int i0 = (blockIdx.x * 256 + threadIdx.x) * 8;   // NN*128 divisible by 8
    float4 a = *(const float4*)(x + i0), b = *(const float4*)(x + i0 + 4);
    float v[8] = {a.x, a.y, a.z, a.w, b.x, b.y, b.z, b.w};
    f16x8 h, l;
#pragma unroll
    for (int j = 0; j < 8; j++) {
        _Float16 hh = (_Float16)v[j];
        h[j] = hh;
        l[j] = (_Float16)(v[j] - (float)hh);
    }
    *(f16x8*)(hi + i0) = h;
    *(f16x8*)(lo + i0) = l;
}

// ---------------------------------------------------------------- aggregation (fp16 gather, fp32 acc, fp16-plane out)
// one wave per dst node; quarter-wave (16 lanes x 16B = one 256B fp16 row),
// 4 edges in flight per quarter. h16 is PRE-SCALED by out_norm.
__global__ __launch_bounds__(256) void agg_k(const float4* __restrict__ h16, const int* __restrict__ rowptr,
                                             const int* __restrict__ col,
                                             _Float16* __restrict__ ahi, _Float16* __restrict__ alo) {
    int w = (int)((blockIdx.x * 256 + threadIdx.x) >> 6);
    if (w >= NN) return;
    int lane = threadIdx.x & 63;
    int q   = lane >> 4;
    int l16 = lane & 15;
    int beg = rowptr[w], end = rowptr[w + 1];
    float acc[8];
#pragma unroll
    for (int j = 0; j < 8; j++) acc[j] = 0.f;

    union HU { float4 f4; __half2 h2[4]; };
    int i = beg + q;
    for (; i + 12 < end; i += 16) {        // per quarter: edges i, i+4, i+8, i+12
        int s0 = col[i], s1 = col[i + 4], s2 = col[i + 8], s3 = col[i + 12];
        HU u0, u1, u2, u3;
        u0.f4 = h16[(size_t)s0 * 16 + l16];
        u1.f4 = h16[(size_t)s1 * 16 + l16];
        u2.f4 = h16[(size_t)s2 * 16 + l16];
        u3.f4 = h16[(size_t)s3 * 16 + l16];
#pragma unroll
        for (int p = 0; p < 4; p++) {
            float2 a = __half22float2(u0.h2[p]);
            float2 b = __half22float2(u1.h2[p]);
            float2 c = __half22float2(u2.h2[p]);
            float2 d = __half22float2(u3.h2[p]);
            acc[2 * p]     += (a.x + b.x) + (c.x + d.x);
            acc[2 * p + 1] += (a.y + b.y) + (c.y + d.y);
        }
    }
    for (; i < end; i += 4) {
        int s = col[i];
        HU u; u.f4 = h16[(size_t)s * 16 + l16];
#pragma unroll
        for (int p = 0; p < 4; p++) {
            float2 a = __half22float2(u.h2[p]);
            acc[2 * p]     += a.x;
            acc[2 * p + 1] += a.y;
        }
    }
#pragma unroll
    for (int mm = 16; mm <= 32; mm <<= 1)
#pragma unroll
        for (int j = 0; j < 8; j++) acc[j] += __shfl_xor(acc[j], mm);
    if (q == 0) {
        f16x8 h, l;
#pragma unroll
        for (int j = 0; j < 8; j++) {
            _Float16 hh = (_Float16)acc[j];
            h[j] = hh;
            l[j] = (_Float16)(acc[j] - (float)hh);
        }
        *(f16x8*)(ahi + (size_t)w * 128 + l16 * 8) = h;
        *(f16x8*)(alo + (size_t)w * 128 + l16 * 8) = l;
    }
}

// ---------------------------------------------------------------- fp16 MFMA GEMM: C ~= Ah@W + Al@W
// A = exact fp16 hi/lo planes. W rounded to fp16, staged once to LDS (NT*4KB).
// 256 threads = 4 waves; wave owns 16 rows, loops nt over all col-tiles ->
// 8 independent 8-MFMA chains per group. Epilogue via per-wave LDS transpose
// (stride-144 rows, conflict-free) -> coalesced 16B row-stores.
// v = (INSC? insc[row]:1)*dot + bias; RELU; OUTSC. OM: 0=f32 scatter, 1=fp16, 2=fp16 planes.
template <int NT, bool RELU, bool INSC, int OM, bool OUTSC>
__global__ __launch_bounds__(256, 4) void gemm_f16_k(
    const _Float16* __restrict__ Ahi, const _Float16* __restrict__ Alo,
    const float* __restrict__ insc,
    const float* __restrict__ W, int wld, const float* __restrict__ bias,
    void* __restrict__ o1, void* __restrict__ o2, const float* __restrict__ outsc,
    int nrows, int ncols, int ngroups) {

    __shared__ __align__(16) _Float16 Bs[NT * 2048];      // [nt][kb][lane] x 8 halves
    __shared__ __align__(16) _Float16 scb[4 * 4 * 144];   // per-wave 4 rows x stride 144

    const int t = threadIdx.x;
    // ---- stage W -> fp16 fragments (one b128 LDS write per fragment)
    for (int f = t; f < NT * 256; f += 256) {
        int nt = f >> 8, kb = (f >> 6) & 3, lane_ = f & 63;
        int m_ = lane_ & 15, kq_ = lane_ >> 4;
        int n = nt * 16 + m_, k0 = kb * 32 + kq_ * 8;
        f16x8 wv;
#pragma unroll
        for (int j = 0; j < 8; j++) {
            float w = (n < ncols) ? W[(size_t)(k0 + j) * wld + n] : 0.f;
            wv[j] = (_Float16)w;
        }
        *(f16x8*)&Bs[f * 8] = wv;
    }
    __syncthreads();

    const int wave = t >> 6, lane = t & 63, m = lane & 15, kq = lane >> 4;
    const int swb = wave * 576;   // scratch base (halves)

    float bv[NT];
#pragma unroll
    for (int nt = 0; nt < NT; nt++) {
        int ccol = nt * 16 + m;
        bv[nt] = (ccol < ncols) ? bias[ccol] : 0.f;
    }

    for (int g = blockIdx.x; g < ngroups; g += gridDim.x) {
        int row0 = g * 64 + wave * 16;
        int row  = row0 + m;
        bool rv  = row < nrows;

        f16x8 ah[4], al[4];
#pragma unroll
        for (int kb = 0; kb < 4; kb++) {
            if (rv) {
                const size_t o = (size_t)row * 128 + kb * 32 + kq * 8;
                ah[kb] = *(const f16x8*)(Ahi + o);
                al[kb] = *(const f16x8*)(Alo + o);
            } else {
                ah[kb] = (f16x8){};
                al[kb] = (f16x8){};
            }
        }

        f32x4 acc[NT];
#pragma unroll
        for (int nt = 0; nt < NT; nt++) {
            f32x4 a = {0.f, 0.f, 0.f, 0.f};
#pragma unroll
            for (int kb = 0; kb < 4; kb++) {
                const f16x8 b = *(const f16x8*)&Bs[((nt * 4 + kb) * 64 + lane) * 8];
                a = __builtin_amdgcn_mfma_f32_16x16x32_f16(ah[kb], b, a, 0, 0, 0);
                a = __builtin_amdgcn_mfma_f32_16x16x32_f16(al[kb], b, a, 0, 0, 0);
            }
            acc[nt] = a;
        }

        if constexpr (OM == 0) {
            // scattered fp32 stores (classifier: ncols=40)
#pragma unroll
            for (int r = 0; r < 4; r++) {
                int crow = row0 + kq * 4 + r;
                if (crow >= nrows) continue;
                float si = INSC ? insc[crow] : 1.f;
                float so = OUTSC ? outsc[crow] : 1.f;
#pragma unroll
                for (int nt = 0; nt < NT; nt++) {
                    int ccol = nt * 16 + m;
                    if (ccol < ncols) {
                        float v = acc[nt][r];
                        if (INSC) v *= si;
                        v += bv[nt];
                        if (RELU) v = fmaxf(v, 0.f);
                        if (OUTSC) v *= so;
                        ((float*)o1)[(size_t)crow * ncols + ccol] = v;
                    }
                }
            }
        } else {
            // coalesced fp16 stores via per-wave LDS transpose
#pragma unroll
            for (int r = 0; r < 4; r++) {
                int crow = row0 + kq * 4 + r;
                bool cva = crow < nrows;
                float si = (INSC && cva) ? insc[crow] : 1.f;
                float so = (OUTSC && cva) ? outsc[crow] : 1.f;
                float vv[NT];
#pragma unroll
                for (int nt = 0; nt < NT; nt++) {
                    float v = acc[nt][r];
                    if (INSC) v *= si;
                    v += bv[nt];
                    if (RELU) v = fmaxf(v, 0.f);
                    if (OUTSC) v *= so;
                    vv[nt] = v;
                    scb[swb + kq * 144 + nt * 16 + m] = (_Float16)v;
                }
                f16x8 hv = *(f16x8*)&scb[swb + kq * 144 + m * 8];
                if (cva) *(f16x8*)((_Float16*)o1 + (size_t)crow * 128 + m * 8) = hv;
                if constexpr (OM == 2) {
#pragma unroll
                    for (int nt = 0; nt < NT; nt++) {
                        _Float16 hh = (_Float16)vv[nt];
                        scb[swb + kq * 144 + nt * 16 + m] = (_Float16)(vv[nt] - (float)hh);
                    }
                    f16x8 lv = *(f16x8*)&scb[swb + kq * 144 + m * 8];
                    if (cva) *(f16x8*)((_Float16*)o2 + (size_t)crow * 128 + m * 8) = lv;
                }
            }
        }
    }
}

// ---------------------------------------------------------------- launch
extern "C" void kernel_launch(void* const* d_in, const int* in_sizes, int n_in,
                              void* d_out, int out_size, void* d_ws, size_t ws_size,
                              hipStream_t stream) {
    const float* x   = (const float*)d_in[0];
    const int*   src = (const int*)d_in[1];
    const int*   dst = (const int*)d_in[2];
    const float* W1  = (const float*)d_in[3];
    const float* b1  = (const float*)d_in[4];
    const float* W2  = (const float*)d_in[5];
    const float* b2  = (const float*)d_in[6];
    const float* Wg  = (const float*)d_in[7];   // [3][128][128]
    const float* bg  = (const float*)d_in[8];   // [3][128]
    const float* Wc  = (const float*)d_in[9];   // [128][40]
    const float* bc  = (const float*)d_in[10];  // [40]
    float* out = (float*)d_out;

    char* ws = (char*)d_ws;
    size_t off = 0;
    auto alloc = [&](size_t bytes) -> void* {
        void* p = ws + off;
        off += (bytes + 255) & ~(size_t)255;
        return p;
    };
    __half*    h16   = (__half*)alloc((size_t)NN * HID * 2);       // 25.6 MB
    _Float16*  ahi   = (_Float16*)alloc((size_t)NN * HID * 2);
    _Float16*  alo   = (_Float16*)alloc((size_t)NN * HID * 2);
    _Float16*  xhi   = (_Float16*)alloc((size_t)NN * HID * 2);     // also conv2-out planes
    _Float16*  xlo   = (_Float16*)alloc((size_t)NN * HID * 2);
    float*  W12    = (float*)alloc(128 * 128 * 4);
    float*  b12    = (float*)alloc(128 * 4);
    float*  onorm  = (float*)alloc((size_t)NN * 4);
    float*  inorm  = (float*)alloc((size_t)NN * 4);
    int*    rowptr = (int*)alloc((size_t)(NN + 1) * 4);
    int*    col    = (int*)alloc((size_t)EE * 4);
    int*    bh_d   = (int*)alloc((size_t)MH * 4);
    int*    bh_s   = (int*)alloc((size_t)MH * 4);
    int*    off_d  = (int*)alloc((size_t)MH * 4);
    int*    off_s  = (int*)alloc((size_t)MH * 4);
    int*    bsum   = (int*)alloc((size_t)NSC * 4);
    int*    boff   = (int*)alloc((size_t)NSC * 4);
    // sort payload buffers alias h16 (consumed before input GEMM writes h16)
    int2* pairs   = (int2*)h16;                          // 12.8 MB
    int*  ssorted = (int*)((char*)h16 + (size_t)EE * 8); // 6.4 MB

    // ---- CSR build (no global atomics)
    bh_both_k<<<NBE, 256, 0, stream>>>(src, dst, bh_d, bh_s);
    scan_sum_k<<<NSC, 256, 0, stream>>>(bh_d, bsum, MH);
    scan_top_k<<<1, 256, 0, stream>>>(bsum, boff, NSC);
    scan_chunk_k<<<NSC, 256, 0, stream>>>(bh_d, boff, off_d, MH);
    scan_sum_k<<<NSC, 256, 0, stream>>>(bh_s, bsum, MH);
    scan_top_k<<<1, 256, 0, stream>>>(bsum, boff, NSC);
    scan_chunk_k<<<NSC, 256, 0, stream>>>(bh_s, boff, off_s, MH);
    scatter_both_k<<<NBE, 256, 0, stream>>>(src, dst, off_d, off_s, pairs, ssorted);
    bucket_csr_k<<<NBUK, 256, 0, stream>>>(pairs, off_d, rowptr, col, inorm);
    bucket_ocnt_k<<<NBUK, 256, 0, stream>>>(ssorted, off_s, onorm);

    // ---- weight fusion + x split (independent of CSR chain)
    w12_k<<<64, 256, 0, stream>>>(W1, W2, W12);
    b12_k<<<1, 128, 0, stream>>>(b1, W2, b2, b12);
    split_k<<<(NN * HID / 8 + 255) / 256, 256, 0, stream>>>(x, xhi, xlo);

    const int ngroups = (NN + 63) / 64;   // 1563

    // h16 = (x @ W12 + b12) * onorm           (fused feature1+feature2)
    gemm_f16_k<8, false, false, 1, true><<<ngroups, 256, 0, stream>>>(
        xhi, xlo, nullptr, W12, 128, b12, h16, nullptr, onorm, NN, 128, ngroups);
    for (int l = 0; l < 3; l++) {
        agg_k<<<(NN * 64 + 255) / 256, 256, 0, stream>>>(
            (const float4*)h16, rowptr, col, ahi, alo);
        if (l < 2) {
            // h16 = relu(inorm*(agg @ Wg) + bg) * onorm
            gemm_f16_k<8, true, true, 1, true><<<ngroups, 256, 0, stream>>>(
                ahi, alo, inorm, Wg + (size_t)l * 128 * 128, 128, bg + (size_t)l * 128,
                h16, nullptr, onorm, NN, 128, ngroups);
        } else {
            // planes = relu(inorm*(agg @ Wg) + bg)   (feed classifier)
            gemm_f16_k<8, true, true, 2, false><<<ngroups, 256, 0, stream>>>(
                ahi, alo, inorm, Wg + (size_t)l * 128 * 128, 128, bg + (size_t)l * 128,
                xhi, xlo, nullptr, NN, 128, ngroups);
        }
    }
    // out = h @ Wc + bc
    gemm_f16_k<3, false, false, 0, false><<<ngroups, 256, 0, stream>>>(
        xhi, xlo, nullptr, Wc, 40, bc, out, nullptr, nullptr, NN, 40, ngroups);
}

// Round 8
// 738.425 us; speedup vs baseline: 1.0133x; 1.0133x over previous
//
#include <hip/hip_runtime.h>
#include <hip/hip_fp16.h>
#include <cstdint>
#include <cstddef>

constexpr int NN  = 100000;
constexpr int EE  = 1600000;
constexpr int HID = 128;
constexpr int NBUK = (NN + 511) / 512;        // 196 buckets of 512 nodes
constexpr int BLKE = 2048;                    // edges per block in bucket passes
constexpr int NBE  = (EE + BLKE - 1) / BLKE;  // 782 edge blocks
constexpr int MH   = NBUK * NBE;              // 153272 flattened hist entries
constexpr int NSC  = (MH + 1023) / 1024;      // 150 scan chunks

typedef float    f32x4 __attribute__((ext_vector_type(4)));
typedef _Float16 f16x8 __attribute__((ext_vector_type(8)));

// ---------------------------------------------------------------- pass 1: per-block bucket histograms (LDS atomics only)
__global__ __launch_bounds__(256) void bh_both_k(const int* __restrict__ src, const int* __restrict__ dst,
                                                 int* __restrict__ bh_d, int* __restrict__ bh_s) {
    __shared__ int hd[NBUK], hs[NBUK];
    int blk = blockIdx.x, t = threadIdx.x;
    for (int i = t; i < NBUK; i += 256) { hd[i] = 0; hs[i] = 0; }
    __syncthreads();
    int e0 = blk * BLKE, e1 = min(e0 + BLKE, EE);
    for (int e = e0 + t; e < e1; e += 256) {
        atomicAdd(&hd[dst[e] >> 9], 1);
        atomicAdd(&hs[src[e] >> 9], 1);
    }
    __syncthreads();
    for (int i = t; i < NBUK; i += 256) {
        bh_d[i * NBE + blk] = hd[i];
        bh_s[i * NBE + blk] = hs[i];
    }
}

// ---------------------------------------------------------------- generic 3-level exclusive scan (length n)
__global__ __launch_bounds__(256) void scan_sum_k(const int* __restrict__ in, int* __restrict__ bsum, int n) {
    __shared__ int sc[256];
    int b = blockIdx.x, t = threadIdx.x;
    int base = b * 1024 + t * 4;
    int s = 0;
#pragma unroll
    for (int j = 0; j < 4; j++) { int idx = base + j; s += (idx < n) ? in[idx] : 0; }
    sc[t] = s; __syncthreads();
    for (int off = 128; off > 0; off >>= 1) {
        if (t < off) sc[t] += sc[t + off];
        __syncthreads();
    }
    if (t == 0) bsum[b] = sc[0];
}

__global__ void scan_top_k(const int* __restrict__ bsum, int* __restrict__ boff, int nb) {
    __shared__ int sc[256];
    int t = threadIdx.x;
    int v = (t < nb) ? bsum[t] : 0;
    sc[t] = v; __syncthreads();
    for (int off = 1; off < 256; off <<= 1) {
        int u = (t >= off) ? sc[t - off] : 0;
        __syncthreads();
        sc[t] += u;
        __syncthreads();
    }
    if (t < nb) boff[t] = sc[t] - v;
}

__global__ __launch_bounds__(256) void scan_chunk_k(const int* __restrict__ in, const int* __restrict__ boff,
                                                    int* __restrict__ out, int n) {
    __shared__ int sc[256];
    int b = blockIdx.x, t = threadIdx.x;
    int base = b * 1024 + t * 4;
    int c[4];
#pragma unroll
    for (int j = 0; j < 4; j++) { int idx = base + j; c[j] = (idx < n) ? in[idx] : 0; }
    int s = c[0] + c[1] + c[2] + c[3];
    sc[t] = s; __syncthreads();
    for (int off = 1; off < 256; off <<= 1) {
        int v = (t >= off) ? sc[t - off] : 0;
        __syncthreads();
        sc[t] += v;
        __syncthreads();
    }
    int excl = sc[t] - s + boff[b];
#pragma unroll
    for (int j = 0; j < 4; j++) {
        int idx = base + j;
        if (idx < n) out[idx] = excl;
        excl += c[j];
    }
}

// ---------------------------------------------------------------- pass 2: scatter into bucket order (LDS cursors)
__global__ __launch_bounds__(256) void scatter_both_k(const int* __restrict__ src, const int* __restrict__ dst,
                                                      const int* __restrict__ off_d, const int* __restrict__ off_s,
                                                      int2* __restrict__ pairs, int* __restrict__ ssorted) {
    __shared__ int cd[NBUK], cs[NBUK];
    int blk = blockIdx.x, t = threadIdx.x;
    for (int i = t; i < NBUK; i += 256) {
        cd[i] = off_d[i * NBE + blk];
        cs[i] = off_s[i * NBE + blk];
    }
    __syncthreads();
    int e0 = blk * BLKE, e1 = min(e0 + BLKE, EE);
    for (int e = e0 + t; e < e1; e += 256) {
        int d = dst[e], s = src[e];
        int pd = atomicAdd(&cd[d >> 9], 1);
        pairs[pd] = make_int2(d, s);
        int ps = atomicAdd(&cs[s >> 9], 1);
        ssorted[ps] = s;
    }
}

// ---------------------------------------------------------------- per-bucket: exact in-deg hist -> inorm, rowptr, col
__global__ __launch_bounds__(256) void bucket_csr_k(const int2* __restrict__ pairs, const int* __restrict__ off_d,
                                                    int* __restrict__ rowptr, int* __restrict__ col,
                                                    float* __restrict__ inorm) {
    __shared__ int hist[512];
    __shared__ int excl[512];
    __shared__ int psum[256];
    int b = blockIdx.x, t = threadIdx.x;
    int base = off_d[b * NBE];
    int endv = (b == NBUK - 1) ? EE : off_d[(b + 1) * NBE];
    hist[t] = 0; hist[t + 256] = 0;
    __syncthreads();
    for (int i = base + t; i < endv; i += 256) atomicAdd(&hist[pairs[i].x & 511], 1);
    __syncthreads();
    int p0 = hist[2 * t], p1 = hist[2 * t + 1];
    int ps = p0 + p1;
    psum[t] = ps; __syncthreads();
    for (int off = 1; off < 256; off <<= 1) {
        int u = (t >= off) ? psum[t - off] : 0;
        __syncthreads();
        psum[t] += u;
        __syncthreads();
    }
    int pex = psum[t] - ps;
    excl[2 * t] = pex; excl[2 * t + 1] = pex + p0;
    __syncthreads();
    int n0 = b * 512;
#pragma unroll
    for (int j = 0; j < 2; j++) {
        int i = 2 * t + j, node = n0 + i;
        if (node < NN) {
            rowptr[node] = base + excl[i];
            int c = hist[i]; if (c < 1) c = 1;
            inorm[node] = rsqrtf((float)c);
        }
    }
    if (b == NBUK - 1 && t == 0) rowptr[NN] = EE;
    __syncthreads();
    for (int i = base + t; i < endv; i += 256) {
        int2 p = pairs[i];
        int pos = base + atomicAdd(&excl[p.x & 511], 1);
        col[pos] = p.y;
    }
}

// ---------------------------------------------------------------- per-bucket: exact out-deg hist -> onorm
__global__ __launch_bounds__(256) void bucket_ocnt_k(const int* __restrict__ ssorted, const int* __restrict__ off_s,
                                                     float* __restrict__ onorm) {
    __shared__ int hist[512];
    int b = blockIdx.x, t = threadIdx.x;
    int base = off_s[b * NBE];
    int endv = (b == NBUK - 1) ? EE : off_s[(b + 1) * NBE];
    hist[t] = 0; hist[t + 256] = 0;
    __syncthreads();
    for (int i = base + t; i < endv; i += 256) atomicAdd(&hist[ssorted[i] & 511], 1);
    __syncthreads();
#pragma unroll
    for (int j = 0; j < 2; j++) {
        int i = t + j * 256, node = b * 512 + i;
        if (node < NN) {
            int c = hist[i]; if (c < 1) c = 1;
            onorm[node] = rsqrtf((float)c);
        }
    }
}

// ---------------------------------------------------------------- W12 = W1 @ W2 ; b12 = b1 @ W2 + b2
__global__ __launch_bounds__(256) void w12_k(const float* __restrict__ W1, const float* __restrict__ W2,
                                             float* __restrict__ W12) {
    int idx = blockIdx.x * 256 + threadIdx.x;   // 0..16383
    int i = idx >> 7, j = idx & 127;
    float a0 = 0.f, a1 = 0.f, a2 = 0.f, a3 = 0.f;
    for (int k = 0; k < 128; k += 4) {
        a0 = fmaf(W1[i * 128 + k],     W2[(k)     * 128 + j], a0);
        a1 = fmaf(W1[i * 128 + k + 1], W2[(k + 1) * 128 + j], a1);
        a2 = fmaf(W1[i * 128 + k + 2], W2[(k + 2) * 128 + j], a2);
        a3 = fmaf(W1[i * 128 + k + 3], W2[(k + 3) * 128 + j], a3);
    }
    W12[idx] = (a0 + a1) + (a2 + a3);
}

__global__ void b12_k(const float* __restrict__ b1, const float* __restrict__ W2,
                      const float* __restrict__ b2, float* __restrict__ b12) {
    int j = threadIdx.x;
    if (j < 128) {
        float acc = b2[j];
        for (int k = 0; k < 128; k++) acc = fmaf(b1[k], W2[k * 128 + j], acc);
        b12[j] = acc;
    }
}

// ---------------------------------------------------------------- aggregation (fp16 gather, fp32 acc, fp32 out)
// one wave per dst node; quarter-wave (16 lanes x 16B = one 256B fp16 row),
// 4 edges in flight per quarter. h16 is PRE-SCALED by out_norm. (R5-proven)
__global__ __launch_bounds__(256) void agg_k(const float4* __restrict__ h16, const int* __restrict__ rowptr,
                                             const int* __restrict__ col, float4* __restrict__ out) {
    int w = (int)((blockIdx.x * 256 + threadIdx.x) >> 6);
    if (w >= NN) return;
    int lane = threadIdx.x & 63;
    int q   = lane >> 4;
    int l16 = lane & 15;
    int beg = rowptr[w], end = rowptr[w + 1];
    float acc[8];
#pragma unroll
    for (int j = 0; j < 8; j++) acc[j] = 0.f;

    union HU { float4 f4; __half2 h2[4]; };
    int i = beg + q;
    for (; i + 12 < end; i += 16) {        // per quarter: edges i, i+4, i+8, i+12
        int s0 = col[i], s1 = col[i + 4], s2 = col[i + 8], s3 = col[i + 12];
        HU u0, u1, u2, u3;
        u0.f4 = h16[(size_t)s0 * 16 + l16];
        u1.f4 = h16[(size_t)s1 * 16 + l16];
        u2.f4 = h16[(size_t)s2 * 16 + l16];
        u3.f4 = h16[(size_t)s3 * 16 + l16];
#pragma unroll
        for (int p = 0; p < 4; p++) {
            float2 a = __half22float2(u0.h2[p]);
            float2 b = __half22float2(u1.h2[p]);
            float2 c = __half22float2(u2.h2[p]);
            float2 d = __half22float2(u3.h2[p]);
            acc[2 * p]     += (a.x + b.x) + (c.x + d.x);
            acc[2 * p + 1] += (a.y + b.y) + (c.y + d.y);
        }
    }
    for (; i < end; i += 4) {
        int s = col[i];
        HU u; u.f4 = h16[(size_t)s * 16 + l16];
#pragma unroll
        for (int p = 0; p < 4; p++) {
            float2 a = __half22float2(u.h2[p]);
            acc[2 * p]     += a.x;
            acc[2 * p + 1] += a.y;
        }
    }
#pragma unroll
    for (int mm = 16; mm <= 32; mm <<= 1)
#pragma unroll
        for (int j = 0; j < 8; j++) acc[j] += __shfl_xor(acc[j], mm);
    if (q == 0) {
        float4 o0, o1;
        o0.x = acc[0]; o0.y = acc[1]; o0.z = acc[2]; o0.w = acc[3];
        o1.x = acc[4]; o1.y = acc[5]; o1.z = acc[6]; o1.w = acc[7];
        out[(size_t)w * 32 + l16 * 2]     = o0;
        out[(size_t)w * 32 + l16 * 2 + 1] = o1;
    }
}

// ---------------------------------------------------------------- fp16-W MFMA GEMM (R5 structure, fp16 2-term)
// out[r][c] = act( insc[r] * (in[r][:] @ W) + bias ) * outsc[r]
// A fp32, inline EXACT fp16 hi/lo split; W rounded fp16 staged once in LDS
// (NT*4KB). C ~= Ah@W + Al@W. 256 thr = 4 waves, wave owns 16 rows, loops nt.
// Memory patterns identical to R5's proven kernel (contiguous fp32 A reads,
// small scattered stores). LDS 16KB -> 4 blocks/CU.
template <int NT, bool RELU, bool INSC, bool OUTSC, bool OUTHALF>
__global__ __launch_bounds__(256, 4) void gemm_h2_k(
    const float* __restrict__ in, const float* __restrict__ insc,
    const float* __restrict__ W, const float* __restrict__ bias,
    void* __restrict__ outp, const float* __restrict__ outsc,
    int nrows, int ncols, int ngroups) {

    __shared__ __align__(16) _Float16 Bs[NT * 2048];   // [nt][kblk(4)][lane(64)][j(8)]
    const int t = threadIdx.x;

    // ---- stage W -> fp16 fragments, once per block (R5 staging pattern)
    if constexpr (NT == 8) {
        for (int j = 0; j < 16; j++) {
            int fi = (j * 256 + t) * 4;              // 4 consecutive floats, same k
            int k = fi >> 7, n0 = fi & 127;
            float4 wv = *(const float4*)(W + fi);
            float wa[4] = {wv.x, wv.y, wv.z, wv.w};
#pragma unroll
            for (int c = 0; c < 4; c++) {
                int n = n0 + c;
                int nt = n >> 4, kblk = k >> 5, ksub = k & 31;
                int lane_ = ((ksub >> 3) << 4) | (n & 15);
                int sidx = ((nt * 4 + kblk) * 64 + lane_) * 8 + (ksub & 7);
                Bs[sidx] = (_Float16)wa[c];
            }
        }
    } else {  // classifier: 40 real cols, pad to NT*16=48
        for (int idx = t; idx < 128 * 64; idx += 256) {
            int k = idx >> 6, n = idx & 63;
            if (n < NT * 16) {
                float w = (n < 40) ? W[k * 40 + n] : 0.f;
                int nt = n >> 4, kblk = k >> 5, ksub = k & 31;
                int lane_ = ((ksub >> 3) << 4) | (n & 15);
                int sidx = ((nt * 4 + kblk) * 64 + lane_) * 8 + (ksub & 7);
                Bs[sidx] = (_Float16)w;
            }
        }
    }
    __syncthreads();   // LDS read-only below

    const int wave = t >> 6;
    const int lane = t & 63;
    const int m    = lane & 15;
    const int kq   = lane >> 4;

    float bv[NT];
#pragma unroll
    for (int nt = 0; nt < NT; nt++) {
        int ccol = nt * 16 + m;
        bv[nt] = (ccol < ncols) ? bias[ccol] : 0.f;
    }

    for (int g = blockIdx.x; g < ngroups; g += gridDim.x) {
        int grow0 = g * 64 + wave * 16;
        int row   = grow0 + m;
        bool rv   = row < nrows;

        // load + exact fp16 hi/lo split of A (contiguous 32B/lane per kb)
        f16x8 Ah[4], Al[4];
#pragma unroll
        for (int kb = 0; kb < 4; kb++) {
            const float* ap = in + (size_t)row * 128 + kb * 32 + kq * 8;
            float4 p0, p1;
            if (rv) { p0 = *(const float4*)ap; p1 = *(const float4*)(ap + 4); }
            else    { p0 = make_float4(0,0,0,0); p1 = make_float4(0,0,0,0); }
            float av[8] = {p0.x, p0.y, p0.z, p0.w, p1.x, p1.y, p1.z, p1.w};
#pragma unroll
            for (int j = 0; j < 8; j++) {
                _Float16 hh = (_Float16)av[j];
                Ah[kb][j] = hh;
                Al[kb][j] = (_Float16)(av[j] - (float)hh);
            }
        }

        // per-row scales (C rows for this lane: grow0 + kq*4 + r)
        int crow0 = grow0 + kq * 4;
        float isr[4], osr[4];
#pragma unroll
        for (int r = 0; r < 4; r++) {
            int crow = crow0 + r;
            bool cva = crow < nrows;
            isr[r] = (INSC && cva) ? insc[crow] : 1.f;
            osr[r] = (OUTSC && cva) ? outsc[crow] : 1.f;
        }

#pragma unroll
        for (int nt = 0; nt < NT; nt++) {
            f32x4 acc = {0.f, 0.f, 0.f, 0.f};
#pragma unroll
            for (int kb = 0; kb < 4; kb++) {
                const f16x8 b = *(const f16x8*)&Bs[((nt * 4 + kb) * 64 + lane) * 8];
                acc = __builtin_amdgcn_mfma_f32_16x16x32_f16(Ah[kb], b, acc, 0, 0, 0);
                acc = __builtin_amdgcn_mfma_f32_16x16x32_f16(Al[kb], b, acc, 0, 0, 0);
            }
            int ccol = nt * 16 + m;
            bool cv = (NT == 8) ? true : (ccol < ncols);
#pragma unroll
            for (int r = 0; r < 4; r++) {
                int crow = crow0 + r;
                if (crow < nrows && cv) {
                    float v = acc[r];
                    if (INSC) v *= isr[r];
                    v += bv[nt];
                    if (RELU) v = fmaxf(v, 0.f);
                    if (OUTSC) v *= osr[r];
                    if (OUTHALF) ((__half*)outp)[(size_t)crow * ncols + ccol] = __float2half_rn(v);
                    else         ((float*)outp)[(size_t)crow * ncols + ccol] = v;
                }
            }
        }
    }
}

// ---------------------------------------------------------------- launch
extern "C" void kernel_launch(void* const* d_in, const int* in_sizes, int n_in,
                              void* d_out, int out_size, void* d_ws, size_t ws_size,
                              hipStream_t stream) {
    const float* x   = (const float*)d_in[0];
    const int*   src = (const int*)d_in[1];
    const int*   dst = (const int*)d_in[2];
    const float* W1  = (const float*)d_in[3];
    const float* b1  = (const float*)d_in[4];
    const float* W2  = (const float*)d_in[5];
    const float* b2  = (const float*)d_in[6];
    const float* Wg  = (const float*)d_in[7];   // [3][128][128]
    const float* bg  = (const float*)d_in[8];   // [3][128]
    const float* Wc  = (const float*)d_in[9];   // [128][40]
    const float* bc  = (const float*)d_in[10];  // [40]
    float* out = (float*)d_out;

    char* ws = (char*)d_ws;
    size_t off = 0;
    auto alloc = [&](size_t bytes) -> void* {
        void* p = ws + off;
        off += (bytes + 255) & ~(size_t)255;
        return p;
    };
    float*  h0     = (float*)alloc((size_t)NN * HID * 4);    // agg out (fp32)
    float*  h1     = (float*)alloc((size_t)NN * HID * 4);    // conv2 out (fp32)
    __half* h16    = (__half*)alloc((size_t)NN * HID * 2);   // agg in (fp16)
    float*  W12    = (float*)alloc(128 * 128 * 4);
    float*  b12    = (float*)alloc(128 * 4);
    float*  onorm  = (float*)alloc((size_t)NN * 4);
    float*  inorm  = (float*)alloc((size_t)NN * 4);
    int*    rowptr = (int*)alloc((size_t)(NN + 1) * 4);
    int*    col    = (int*)alloc((size_t)EE * 4);
    int*    bh_d   = (int*)alloc((size_t)MH * 4);
    int*    bh_s   = (int*)alloc((size_t)MH * 4);
    int*    off_d  = (int*)alloc((size_t)MH * 4);
    int*    off_s  = (int*)alloc((size_t)MH * 4);
    int*    bsum   = (int*)alloc((size_t)NSC * 4);
    int*    boff   = (int*)alloc((size_t)NSC * 4);
    // sort payload buffers alias h0 (consumed by bucket kernels before agg writes h0)
    int2* pairs   = (int2*)h0;                          // 12.8 MB
    int*  ssorted = (int*)((char*)h0 + (size_t)EE * 8); // 6.4 MB

    // ---- CSR build (no global atomics)
    bh_both_k<<<NBE, 256, 0, stream>>>(src, dst, bh_d, bh_s);
    scan_sum_k<<<NSC, 256, 0, stream>>>(bh_d, bsum, MH);
    scan_top_k<<<1, 256, 0, stream>>>(bsum, boff, NSC);
    scan_chunk_k<<<NSC, 256, 0, stream>>>(bh_d, boff, off_d, MH);
    scan_sum_k<<<NSC, 256, 0, stream>>>(bh_s, bsum, MH);
    scan_top_k<<<1, 256, 0, stream>>>(bsum, boff, NSC);
    scan_chunk_k<<<NSC, 256, 0, stream>>>(bh_s, boff, off_s, MH);
    scatter_both_k<<<NBE, 256, 0, stream>>>(src, dst, off_d, off_s, pairs, ssorted);
    bucket_csr_k<<<NBUK, 256, 0, stream>>>(pairs, off_d, rowptr, col, inorm);
    bucket_ocnt_k<<<NBUK, 256, 0, stream>>>(ssorted, off_s, onorm);

    // ---- weight fusion (independent of CSR chain)
    w12_k<<<64, 256, 0, stream>>>(W1, W2, W12);
    b12_k<<<1, 128, 0, stream>>>(b1, W2, b2, b12);

    const int ngroups = (NN + 63) / 64;   // 1563

    // h16 = (x @ W12 + b12) * onorm           (fused feature1+feature2)
    gemm_h2_k<8, false, false, true, true><<<ngroups, 256, 0, stream>>>(
        x, nullptr, W12, b12, h16, onorm, NN, 128, ngroups);
    for (int l = 0; l < 3; l++) {
        agg_k<<<(NN * 64 + 255) / 256, 256, 0, stream>>>(
            (const float4*)h16, rowptr, col, (float4*)h0);
        if (l < 2) {
            // h16 = relu(inorm * (h0 @ Wg) + bg) * onorm
            gemm_h2_k<8, true, true, true, true><<<ngroups, 256, 0, stream>>>(
                h0, inorm, Wg + (size_t)l * 128 * 128, bg + (size_t)l * 128, h16, onorm, NN, 128, ngroups);
        } else {
            // h1 = relu(inorm * (h0 @ Wg) + bg)     (fp32, feeds classifier)
            gemm_h2_k<8, true, true, false, false><<<ngroups, 256, 0, stream>>>(
                h0, inorm, Wg + (size_t)l * 128 * 128, bg + (size_t)l * 128, h1, nullptr, NN, 128, ngroups);
        }
    }
    // out = h1 @ Wc + bc
    gemm_h2_k<3, false, false, false, false><<<ngroups, 256, 0, stream>>>(
        h1, nullptr, Wc, bc, out, nullptr, NN, 40, ngroups);
}

// Round 9
// 583.434 us; speedup vs baseline: 1.2825x; 1.2657x over previous
//
#include <hip/hip_runtime.h>
#include <hip/hip_fp16.h>
#include <cstdint>
#include <cstddef>

constexpr int NN  = 100000;
constexpr int EE  = 1600000;
constexpr int HID = 128;
constexpr int NBUK = (NN + 511) / 512;        // 196 buckets of 512 nodes
constexpr int BLKE = 2048;                    // edges per block in bucket passes
constexpr int NBE  = (EE + BLKE - 1) / BLKE;  // 782 edge blocks
constexpr int MH   = NBUK * NBE;              // 153272 flattened hist entries
constexpr int NSC  = (MH + 1023) / 1024;      // 150 scan chunks

typedef float f32x4_t __attribute__((ext_vector_type(4)));
typedef short bf16x8_t __attribute__((ext_vector_type(8)));

static __device__ __forceinline__ short f2bf(float f) {
    union { float f; unsigned u; } x; x.f = f;
    unsigned r = x.u + 0x7FFF + ((x.u >> 16) & 1);   // RN-even
    return (short)(r >> 16);
}
static __device__ __forceinline__ float bf2f(short b) {
    union { unsigned u; float f; } x; x.u = ((unsigned)(unsigned short)b) << 16;
    return x.f;
}

// ---------------------------------------------------------------- pass 1: per-block bucket histograms (LDS atomics only)
__global__ __launch_bounds__(256) void bh_both_k(const int* __restrict__ src, const int* __restrict__ dst,
                                                 int* __restrict__ bh_d, int* __restrict__ bh_s) {
    __shared__ int hd[NBUK], hs[NBUK];
    int blk = blockIdx.x, t = threadIdx.x;
    for (int i = t; i < NBUK; i += 256) { hd[i] = 0; hs[i] = 0; }
    __syncthreads();
    int e0 = blk * BLKE, e1 = min(e0 + BLKE, EE);
    for (int e = e0 + t; e < e1; e += 256) {
        atomicAdd(&hd[dst[e] >> 9], 1);
        atomicAdd(&hs[src[e] >> 9], 1);
    }
    __syncthreads();
    for (int i = t; i < NBUK; i += 256) {
        bh_d[i * NBE + blk] = hd[i];
        bh_s[i * NBE + blk] = hs[i];
    }
}

// ---------------------------------------------------------------- generic 3-level exclusive scan (length n)
__global__ __launch_bounds__(256) void scan_sum_k(const int* __restrict__ in, int* __restrict__ bsum, int n) {
    __shared__ int sc[256];
    int b = blockIdx.x, t = threadIdx.x;
    int base = b * 1024 + t * 4;
    int s = 0;
#pragma unroll
    for (int j = 0; j < 4; j++) { int idx = base + j; s += (idx < n) ? in[idx] : 0; }
    sc[t] = s; __syncthreads();
    for (int off = 128; off > 0; off >>= 1) {
        if (t < off) sc[t] += sc[t + off];
        __syncthreads();
    }
    if (t == 0) bsum[b] = sc[0];
}

__global__ void scan_top_k(const int* __restrict__ bsum, int* __restrict__ boff, int nb) {
    __shared__ int sc[256];
    int t = threadIdx.x;
    int v = (t < nb) ? bsum[t] : 0;
    sc[t] = v; __syncthreads();
    for (int off = 1; off < 256; off <<= 1) {
        int u = (t >= off) ? sc[t - off] : 0;
        __syncthreads();
        sc[t] += u;
        __syncthreads();
    }
    if (t < nb) boff[t] = sc[t] - v;
}

__global__ __launch_bounds__(256) void scan_chunk_k(const int* __restrict__ in, const int* __restrict__ boff,
                                                    int* __restrict__ out, int n) {
    __shared__ int sc[256];
    int b = blockIdx.x, t = threadIdx.x;
    int base = b * 1024 + t * 4;
    int c[4];
#pragma unroll
    for (int j = 0; j < 4; j++) { int idx = base + j; c[j] = (idx < n) ? in[idx] : 0; }
    int s = c[0] + c[1] + c[2] + c[3];
    sc[t] = s; __syncthreads();
    for (int off = 1; off < 256; off <<= 1) {
        int v = (t >= off) ? sc[t - off] : 0;
        __syncthreads();
        sc[t] += v;
        __syncthreads();
    }
    int excl = sc[t] - s + boff[b];
#pragma unroll
    for (int j = 0; j < 4; j++) {
        int idx = base + j;
        if (idx < n) out[idx] = excl;
        excl += c[j];
    }
}

// ---------------------------------------------------------------- pass 2: scatter into bucket order (LDS cursors)
__global__ __launch_bounds__(256) void scatter_both_k(const int* __restrict__ src, const int* __restrict__ dst,
                                                      const int* __restrict__ off_d, const int* __restrict__ off_s,
                                                      int2* __restrict__ pairs, int* __restrict__ ssorted) {
    __shared__ int cd[NBUK], cs[NBUK];
    int blk = blockIdx.x, t = threadIdx.x;
    for (int i = t; i < NBUK; i += 256) {
        cd[i] = off_d[i * NBE + blk];
        cs[i] = off_s[i * NBE + blk];
    }
    __syncthreads();
    int e0 = blk * BLKE, e1 = min(e0 + BLKE, EE);
    for (int e = e0 + t; e < e1; e += 256) {
        int d = dst[e], s = src[e];
        int pd = atomicAdd(&cd[d >> 9], 1);
        pairs[pd] = make_int2(d, s);
        int ps = atomicAdd(&cs[s >> 9], 1);
        ssorted[ps] = s;
    }
}

// ---------------------------------------------------------------- per-bucket: exact in-deg hist -> inorm, rowptr, col
__global__ __launch_bounds__(256) void bucket_csr_k(const int2* __restrict__ pairs, const int* __restrict__ off_d,
                                                    int* __restrict__ rowptr, int* __restrict__ col,
                                                    float* __restrict__ inorm) {
    __shared__ int hist[512];
    __shared__ int excl[512];
    __shared__ int psum[256];
    int b = blockIdx.x, t = threadIdx.x;
    int base = off_d[b * NBE];
    int endv = (b == NBUK - 1) ? EE : off_d[(b + 1) * NBE];
    hist[t] = 0; hist[t + 256] = 0;
    __syncthreads();
    for (int i = base + t; i < endv; i += 256) atomicAdd(&hist[pairs[i].x & 511], 1);
    __syncthreads();
    int p0 = hist[2 * t], p1 = hist[2 * t + 1];
    int ps = p0 + p1;
    psum[t] = ps; __syncthreads();
    for (int off = 1; off < 256; off <<= 1) {
        int u = (t >= off) ? psum[t - off] : 0;
        __syncthreads();
        psum[t] += u;
        __syncthreads();
    }
    int pex = psum[t] - ps;
    excl[2 * t] = pex; excl[2 * t + 1] = pex + p0;
    __syncthreads();
    int n0 = b * 512;
#pragma unroll
    for (int j = 0; j < 2; j++) {
        int i = 2 * t + j, node = n0 + i;
        if (node < NN) {
            rowptr[node] = base + excl[i];
            int c = hist[i]; if (c < 1) c = 1;
            inorm[node] = rsqrtf((float)c);
        }
    }
    if (b == NBUK - 1 && t == 0) rowptr[NN] = EE;
    __syncthreads();
    for (int i = base + t; i < endv; i += 256) {
        int2 p = pairs[i];
        int pos = base + atomicAdd(&excl[p.x & 511], 1);
        col[pos] = p.y;
    }
}

// ---------------------------------------------------------------- per-bucket: exact out-deg hist -> onorm
__global__ __launch_bounds__(256) void bucket_ocnt_k(const int* __restrict__ ssorted, const int* __restrict__ off_s,
                                                     float* __restrict__ onorm) {
    __shared__ int hist[512];
    int b = blockIdx.x, t = threadIdx.x;
    int base = off_s[b * NBE];
    int endv = (b == NBUK - 1) ? EE : off_s[(b + 1) * NBE];
    hist[t] = 0; hist[t + 256] = 0;
    __syncthreads();
    for (int i = base + t; i < endv; i += 256) atomicAdd(&hist[ssorted[i] & 511], 1);
    __syncthreads();
#pragma unroll
    for (int j = 0; j < 2; j++) {
        int i = t + j * 256, node = b * 512 + i;
        if (node < NN) {
            int c = hist[i]; if (c < 1) c = 1;
            onorm[node] = rsqrtf((float)c);
        }
    }
}

// ---------------------------------------------------------------- W12 = W1 @ W2 ; b12 = b1 @ W2 + b2
__global__ __launch_bounds__(256) void w12_k(const float* __restrict__ W1, const float* __restrict__ W2,
                                             float* __restrict__ W12) {
    int idx = blockIdx.x * 256 + threadIdx.x;   // 0..16383
    int i = idx >> 7, j = idx & 127;
    float a0 = 0.f, a1 = 0.f, a2 = 0.f, a3 = 0.f;
    for (int k = 0; k < 128; k += 4) {
        a0 = fmaf(W1[i * 128 + k],     W2[(k)     * 128 + j], a0);
        a1 = fmaf(W1[i * 128 + k + 1], W2[(k + 1) * 128 + j], a1);
        a2 = fmaf(W1[i * 128 + k + 2], W2[(k + 2) * 128 + j], a2);
        a3 = fmaf(W1[i * 128 + k + 3], W2[(k + 3) * 128 + j], a3);
    }
    W12[idx] = (a0 + a1) + (a2 + a3);
}

__global__ void b12_k(const float* __restrict__ b1, const float* __restrict__ W2,
                      const float* __restrict__ b2, float* __restrict__ b12) {
    int j = threadIdx.x;
    if (j < 128) {
        float acc = b2[j];
        for (int k = 0; k < 128; k++) acc = fmaf(b1[k], W2[k * 128 + j], acc);
        b12[j] = acc;
    }
}

// ---------------------------------------------------------------- aggregation (fp16 gather, fp32 acc, fp32 out)
// R5-proven: one wave per dst node; quarter-wave (16 lanes x 16B = one 256B
// fp16 row), 4 edges in flight per quarter. h16 is PRE-SCALED by out_norm.
__global__ __launch_bounds__(256) void agg_k(const float4* __restrict__ h16, const int* __restrict__ rowptr,
                                             const int* __restrict__ col, float4* __restrict__ out) {
    int w = (int)((blockIdx.x * 256 + threadIdx.x) >> 6);
    if (w >= NN) return;
    int lane = threadIdx.x & 63;
    int q   = lane >> 4;
    int l16 = lane & 15;
    int beg = rowptr[w], end = rowptr[w + 1];
    float acc[8];
#pragma unroll
    for (int j = 0; j < 8; j++) acc[j] = 0.f;

    union HU { float4 f4; __half2 h2[4]; };
    int i = beg + q;
    for (; i + 12 < end; i += 16) {        // per quarter: edges i, i+4, i+8, i+12
        int s0 = col[i], s1 = col[i + 4], s2 = col[i + 8], s3 = col[i + 12];
        HU u0, u1, u2, u3;
        u0.f4 = h16[(size_t)s0 * 16 + l16];
        u1.f4 = h16[(size_t)s1 * 16 + l16];
        u2.f4 = h16[(size_t)s2 * 16 + l16];
        u3.f4 = h16[(size_t)s3 * 16 + l16];
#pragma unroll
        for (int p = 0; p < 4; p++) {
            float2 a = __half22float2(u0.h2[p]);
            float2 b = __half22float2(u1.h2[p]);
            float2 c = __half22float2(u2.h2[p]);
            float2 d = __half22float2(u3.h2[p]);
            acc[2 * p]     += (a.x + b.x) + (c.x + d.x);
            acc[2 * p + 1] += (a.y + b.y) + (c.y + d.y);
        }
    }
    for (; i < end; i += 4) {
        int s = col[i];
        HU u; u.f4 = h16[(size_t)s * 16 + l16];
#pragma unroll
        for (int p = 0; p < 4; p++) {
            float2 a = __half22float2(u.h2[p]);
            acc[2 * p]     += a.x;
            acc[2 * p + 1] += a.y;
        }
    }
#pragma unroll
    for (int mm = 16; mm <= 32; mm <<= 1)
#pragma unroll
        for (int j = 0; j < 8; j++) acc[j] += __shfl_xor(acc[j], mm);
    if (q == 0) {
        float4 o0, o1;
        o0.x = acc[0]; o0.y = acc[1]; o0.z = acc[2]; o0.w = acc[3];
        o1.x = acc[4]; o1.y = acc[5]; o1.z = acc[6]; o1.w = acc[7];
        out[(size_t)w * 32 + l16 * 2]     = o0;
        out[(size_t)w * 32 + l16 * 2 + 1] = o1;
    }
}

// ---------------------------------------------------------------- split-bf16 MFMA GEMM (R5-proven, verbatim)
// out[r][c] = act( (inscale[r] * in[r][:]) @ W + bias ) * outscale[r]
// OUTHALF: store output as fp16 (consumed only by agg_k)
template <int NT, bool RELU, bool INSCALE, bool OUTSCALE, bool OUTHALF>
__global__ __launch_bounds__(256) void mfma_gemm_k(
    const float* __restrict__ in, const float* __restrict__ inscale,
    const float* __restrict__ W, const float* __restrict__ bias,
    void* __restrict__ outp, const float* __restrict__ outscale,
    int nrows, int ncols, int ngroups) {

    __shared__ short Bh[NT * 2048];   // [nt][kblk(4)][lane(64)][j(8)]
    __shared__ short Bl[NT * 2048];

    const int t = threadIdx.x;

    if constexpr (NT == 8) {
        for (int j = 0; j < 16; j++) {
            int fi = (j * 256 + t) * 4;
            int k = fi >> 7, n0 = fi & 127;
            float4 wv = *(const float4*)(W + fi);
            float wa[4] = {wv.x, wv.y, wv.z, wv.w};
#pragma unroll
            for (int c = 0; c < 4; c++) {
                int n = n0 + c;
                int nt = n >> 4, kblk = k >> 5, ksub = k & 31;
                int lane_ = ((ksub >> 3) << 4) | (n & 15);
                int sidx = ((nt * 4 + kblk) * 64 + lane_) * 8 + (ksub & 7);
                short hi = f2bf(wa[c]);
                short lo = f2bf(wa[c] - bf2f(hi));
                Bh[sidx] = hi; Bl[sidx] = lo;
            }
        }
    } else {  // classifier: 40 real cols, pad to NT*16=48
        for (int idx = t; idx < 128 * 64; idx += 256) {
            int k = idx >> 6, n = idx & 63;
            if (n < NT * 16) {
                float w = (n < 40) ? W[k * 40 + n] : 0.f;
                int nt = n >> 4, kblk = k >> 5, ksub = k & 31;
                int lane_ = ((ksub >> 3) << 4) | (n & 15);
                int sidx = ((nt * 4 + kblk) * 64 + lane_) * 8 + (ksub & 7);
                short hi = f2bf(w);
                short lo = f2bf(w - bf2f(hi));
                Bh[sidx] = hi; Bl[sidx] = lo;
            }
        }
    }
    __syncthreads();   // LDS read-only below

    const int wave = t >> 6;
    const int lane = t & 63;
    const int m    = lane & 15;
    const int kq   = lane >> 4;

    for (int g = blockIdx.x; g < ngroups; g += gridDim.x) {
        int grow0 = g * 64 + wave * 16;
        int row   = grow0 + m;
        bool rv   = row < nrows;

        bf16x8_t Ah[4], Al[4];
        float s = 1.f;
        if (INSCALE && rv) s = inscale[row];
#pragma unroll
        for (int kb = 0; kb < 4; kb++) {
            const float* ap = in + (size_t)row * 128 + kb * 32 + kq * 8;
            float4 p0, p1;
            if (rv) { p0 = *(const float4*)ap; p1 = *(const float4*)(ap + 4); }
            else    { p0 = make_float4(0,0,0,0); p1 = make_float4(0,0,0,0); }
            float av[8] = {p0.x, p0.y, p0.z, p0.w, p1.x, p1.y, p1.z, p1.w};
#pragma unroll
            for (int j = 0; j < 8; j++) {
                float v = INSCALE ? av[j] * s : av[j];
                short hi = f2bf(v);
                Ah[kb][j] = hi;
                Al[kb][j] = f2bf(v - bf2f(hi));
            }
        }

        int crow0 = grow0 + kq * 4;
        float osr[4];
#pragma unroll
        for (int r = 0; r < 4; r++) {
            int crow = crow0 + r;
            osr[r] = (OUTSCALE && crow < nrows) ? outscale[crow] : 1.f;
        }

#pragma unroll
        for (int nt = 0; nt < NT; nt++) {
            f32x4_t acc = {0.f, 0.f, 0.f, 0.f};
#pragma unroll
            for (int kb = 0; kb < 4; kb++) {
                const bf16x8_t bh = *(const bf16x8_t*)&Bh[((nt * 4 + kb) * 64 + lane) * 8];
                const bf16x8_t bl = *(const bf16x8_t*)&Bl[((nt * 4 + kb) * 64 + lane) * 8];
                acc = __builtin_amdgcn_mfma_f32_16x16x32_bf16(Ah[kb], bh, acc, 0, 0, 0);
                acc = __builtin_amdgcn_mfma_f32_16x16x32_bf16(Al[kb], bh, acc, 0, 0, 0);
                acc = __builtin_amdgcn_mfma_f32_16x16x32_bf16(Ah[kb], bl, acc, 0, 0, 0);
            }
            int ccol = nt * 16 + m;
            bool cv = (NT == 8) ? true : (ccol < ncols);
            float bv = cv ? bias[ccol] : 0.f;
#pragma unroll
            for (int r = 0; r < 4; r++) {
                int crow = crow0 + r;
                if (crow < nrows && cv) {
                    float v = acc[r] + bv;
                    if (RELU) v = fmaxf(v, 0.f);
                    v *= osr[r];
                    if (OUTHALF) ((__half*)outp)[(size_t)crow * ncols + ccol] = __float2half_rn(v);
                    else         ((float*)outp)[(size_t)crow * ncols + ccol] = v;
                }
            }
        }
    }
}

// ---------------------------------------------------------------- launch
extern "C" void kernel_launch(void* const* d_in, const int* in_sizes, int n_in,
                              void* d_out, int out_size, void* d_ws, size_t ws_size,
                              hipStream_t stream) {
    const float* x   = (const float*)d_in[0];
    const int*   src = (const int*)d_in[1];
    const int*   dst = (const int*)d_in[2];
    const float* W1  = (const float*)d_in[3];
    const float* b1  = (const float*)d_in[4];
    const float* W2  = (const float*)d_in[5];
    const float* b2  = (const float*)d_in[6];
    const float* Wg  = (const float*)d_in[7];   // [3][128][128]
    const float* bg  = (const float*)d_in[8];   // [3][128]
    const float* Wc  = (const float*)d_in[9];   // [128][40]
    const float* bc  = (const float*)d_in[10];  // [40]
    float* out = (float*)d_out;

    char* ws = (char*)d_ws;
    size_t off = 0;
    auto alloc = [&](size_t bytes) -> void* {
        void* p = ws + off;
        off += (bytes + 255) & ~(size_t)255;
        return p;
    };
    float*  h0     = (float*)alloc((size_t)NN * HID * 4);    // agg out (fp32)
    float*  h1     = (float*)alloc((size_t)NN * HID * 4);    // conv2 out (fp32)
    __half* h16    = (__half*)alloc((size_t)NN * HID * 2);   // agg in (fp16)
    float*  W12    = (float*)alloc(128 * 128 * 4);
    float*  b12    = (float*)alloc(128 * 4);
    float*  onorm  = (float*)alloc((size_t)NN * 4);
    float*  inorm  = (float*)alloc((size_t)NN * 4);
    int*    rowptr = (int*)alloc((size_t)(NN + 1) * 4);
    int*    col    = (int*)alloc((size_t)EE * 4);
    int*    bh_d   = (int*)alloc((size_t)MH * 4);
    int*    bh_s   = (int*)alloc((size_t)MH * 4);
    int*    off_d  = (int*)alloc((size_t)MH * 4);
    int*    off_s  = (int*)alloc((size_t)MH * 4);
    int*    bsum   = (int*)alloc((size_t)NSC * 4);
    int*    boff   = (int*)alloc((size_t)NSC * 4);
    // sort payload buffers alias h0 (consumed by bucket kernels before agg writes h0)
    int2* pairs   = (int2*)h0;                          // 12.8 MB
    int*  ssorted = (int*)((char*)h0 + (size_t)EE * 8); // 6.4 MB

    // ---- CSR build (no global atomics)
    bh_both_k<<<NBE, 256, 0, stream>>>(src, dst, bh_d, bh_s);
    scan_sum_k<<<NSC, 256, 0, stream>>>(bh_d, bsum, MH);
    scan_top_k<<<1, 256, 0, stream>>>(bsum, boff, NSC);
    scan_chunk_k<<<NSC, 256, 0, stream>>>(bh_d, boff, off_d, MH);
    scan_sum_k<<<NSC, 256, 0, stream>>>(bh_s, bsum, MH);
    scan_top_k<<<1, 256, 0, stream>>>(bsum, boff, NSC);
    scan_chunk_k<<<NSC, 256, 0, stream>>>(bh_s, boff, off_s, MH);
    scatter_both_k<<<NBE, 256, 0, stream>>>(src, dst, off_d, off_s, pairs, ssorted);
    bucket_csr_k<<<NBUK, 256, 0, stream>>>(pairs, off_d, rowptr, col, inorm);
    bucket_ocnt_k<<<NBUK, 256, 0, stream>>>(ssorted, off_s, onorm);

    // ---- weight fusion (independent of CSR chain)
    w12_k<<<64, 256, 0, stream>>>(W1, W2, W12);
    b12_k<<<1, 128, 0, stream>>>(b1, W2, b2, b12);

    const int ngroups = (NN + 63) / 64;   // 1563
    const int ggrid   = 512;              // R5-proven: 2 blocks/CU persistent

    // h16 = (x @ W12 + b12) * onorm           (fused feature1+feature2)
    mfma_gemm_k<8, false, false, true, true><<<ggrid, 256, 0, stream>>>(
        x, nullptr, W12, b12, h16, onorm, NN, 128, ngroups);
    for (int l = 0; l < 3; l++) {
        agg_k<<<(NN * 64 + 255) / 256, 256, 0, stream>>>(
            (const float4*)h16, rowptr, col, (float4*)h0);
        if (l < 2) {
            // h16 = relu(inorm*(h0 @ Wg) + bg) * onorm   (fp16 out, feeds agg)
            mfma_gemm_k<8, true, true, true, true><<<ggrid, 256, 0, stream>>>(
                h0, inorm, Wg + (size_t)l * 128 * 128, bg + (size_t)l * 128, h16, onorm, NN, 128, ngroups);
        } else {
            // h1 = relu(inorm*(h0 @ Wg) + bg)            (fp32, feeds classifier)
            mfma_gemm_k<8, true, true, false, false><<<ggrid, 256, 0, stream>>>(
                h0, inorm, Wg + (size_t)l * 128 * 128, bg + (size_t)l * 128, h1, nullptr, NN, 128, ngroups);
        }
    }
    // out = h1 @ Wc + bc
    mfma_gemm_k<3, false, false, false, false><<<ggrid, 256, 0, stream>>>(
        h1, nullptr, Wc, bc, out, nullptr, NN, 40, ngroups);
}